// Round 10
// baseline (163.849 us; speedup 1.0000x reference)
//
#include <hip/hip_runtime.h>
#include <math.h>

#define KNBR 16
#define DIM 64
#define NREL 32
#define WPB 4   // batch elements (one wave each) per 256-thread block

// v_readlane_b32: cross-lane read -> SGPR, no LDS-pipe traffic. Lane index
// must be imm or SGPR-uniform (all uses are unrolled consts / uniform vars).
__device__ __forceinline__ int irl(int v, int l) {
    return __builtin_amdgcn_readlane(v, l);
}
__device__ __forceinline__ float frl(float v, int l) {
    return __int_as_float(__builtin_amdgcn_readlane(__float_as_int(v), l));
}

typedef __attribute__((address_space(3))) float       lds_f;
typedef const __attribute__((address_space(1))) float glb_f;

// s_waitcnt imm encoding (gfx9+): vmcnt[3:0]=bits3:0, vmcnt[5:4]=bits15:14,
// expcnt=bits6:4, lgkmcnt=bits11:8. vmcnt(16)=0x4F70, vmcnt(0)=0x0F70
// (exp/lgkm left at max = don't wait).

// R10 vs R8/R9: hop-2 rows stream through LDS via global_load_lds (no VGPR
// destination -> queue depth not collapsible by the register allocator),
// double-buffered per-wave with explicit vmcnt(16) waits. vmcnt retires
// in order (m135), so <=16 outstanding == previous chunk complete.
__global__ __launch_bounds__(256, 2) void kgnnls_kernel(
    const int* __restrict__ u_ids, const int* __restrict__ i_ids,
    const int* __restrict__ adj_entity, const int* __restrict__ adj_relation,
    const float* __restrict__ user_emb, const float* __restrict__ entity_emb,
    const float* __restrict__ relation_emb,
    const float* __restrict__ W0, const float* __restrict__ b0,
    const float* __restrict__ W1, const float* __restrict__ b1,
    float* __restrict__ out, int B)
{
    const int tid  = threadIdx.x;
    const int wave = tid >> 6;
    const int lane = tid & 63;          // dual role: dim index d / output index e
    int b = blockIdx.x * WPB + wave;
    if (b >= B) b = B - 1;              // duplicate work, benign duplicate write

    __shared__ float xbuf[WPB][17][DIM];
    __shared__ float uebuf[WPB][DIM];
    __shared__ float stage[WPB][2][KNBR][DIM];  // per-wave double-buffered hop-2 rows

    const int u  = u_ids[b];
    const int i0 = i_ids[b];

    const float ue = user_emb[u * DIM + lane];
    uebuf[wave][lane] = ue;
    const float bias0 = b0[lane];

    __syncthreads();

    // s[r] at lane r (r < 33): s = (1/64) * dot(ue, relation_emb[r])
    float s_val = 0.f;
    if (lane < NREL + 1) {
        const float4* rrow = (const float4*)(relation_emb + lane * DIM);
        const float4* ub   = (const float4*)uebuf[wave];
        float acc = 0.f;
        #pragma unroll
        for (int q = 0; q < 16; ++q) {
            float4 r4 = rrow[q];
            float4 u4 = ub[q];   // same address across lanes -> LDS broadcast
            acc += r4.x*u4.x + r4.y*u4.y + r4.z*u4.z + r4.w*u4.w;
        }
        s_val = acc * (1.0f / DIM);
    }

    // hop-0 neighbor/relation indices at lanes 0..15
    int e1k = 0, r0k = 0;
    if (lane < KNBR) {
        e1k = adj_entity  [i0 * KNBR + lane];
        r0k = adj_relation[i0 * KNBR + lane];
    }

    // softmax over k (16) for hop-0 scores, valid at lanes 0..15
    float sc0 = __shfl(s_val, r0k);      // data-dependent lane -> bpermute
    float m0 = sc0;
    m0 = fmaxf(m0, __shfl_xor(m0, 1));
    m0 = fmaxf(m0, __shfl_xor(m0, 2));
    m0 = fmaxf(m0, __shfl_xor(m0, 4));
    m0 = fmaxf(m0, __shfl_xor(m0, 8));
    float ex0 = __expf(sc0 - m0);
    float z0 = ex0;
    z0 += __shfl_xor(z0, 1);
    z0 += __shfl_xor(z0, 2);
    z0 += __shfl_xor(z0, 4);
    z0 += __shfl_xor(z0, 8);
    const float attn0 = ex0 / z0;     // lanes 0..15 hold attn0[k]

    // hop-1: lane handles k = lane>>2, j in [4*(lane&3), +4)
    const int kk = lane >> 2;
    const int jb = (lane & 3) * 4;
    const int ek = __shfl(e1k, kk);   // per-lane index -> bpermute
    const int4 e2i = *(const int4*)(adj_entity  + ek * KNBR + jb);
    const int4 r2i = *(const int4*)(adj_relation + ek * KNBR + jb);
    int e2idx[4] = { e2i.x, e2i.y, e2i.z, e2i.w };

    float sc1[4];
    sc1[0] = __shfl(s_val, r2i.x);    // data-dependent lanes -> bpermute
    sc1[1] = __shfl(s_val, r2i.y);
    sc1[2] = __shfl(s_val, r2i.z);
    sc1[3] = __shfl(s_val, r2i.w);

    // softmax over the 16 j's: intra-lane over 4 + xor over lanes {1,2}
    float m1 = fmaxf(fmaxf(sc1[0], sc1[1]), fmaxf(sc1[2], sc1[3]));
    m1 = fmaxf(m1, __shfl_xor(m1, 1));
    m1 = fmaxf(m1, __shfl_xor(m1, 2));
    float a1[4];
    float z1 = 0.f;
    #pragma unroll
    for (int t = 0; t < 4; ++t) { a1[t] = __expf(sc1[t] - m1); z1 += a1[t]; }
    z1 += __shfl_xor(z1, 1);
    z1 += __shfl_xor(z1, 2);
    const float inv_z1 = 1.0f / z1;
    #pragma unroll
    for (int t = 0; t < 4; ++t) a1[t] *= inv_z1;

    // ---- Gather phase ----
    // v1 rows (17 incl. self) stay in VGPRs; hop-2 rows stream through LDS.
    float v1a[KNBR];
    #pragma unroll
    for (int k = 0; k < KNBR; ++k) {
        const int ei = irl(e1k, k);                    // imm lane -> SGPR
        v1a[k] = entity_emb[(size_t)ei * DIM + lane];  // SGPR base + lane*4
    }
    const float ev0 = entity_emb[(size_t)i0 * DIM + lane];
    __builtin_amdgcn_sched_barrier(0);  // keep v1a issues above the pipeline

    // issue chunk 0 (k=0): 16 hop-2 rows -> stage[wave][0]
    #pragma unroll
    for (int j = 0; j < 16; ++j) {
        const int ei2 = irl(e2idx[j & 3], (j >> 2));
        glb_f* g = (glb_f*)(entity_emb + (size_t)ei2 * DIM + lane);
        lds_f* l = (lds_f*)&stage[wave][0][j][0];      // wave-uniform base
        __builtin_amdgcn_global_load_lds(g, l, 4, 0, 0);
    }

    float agg0 = 0.f;
    #pragma unroll
    for (int k = 0; k < KNBR; ++k) {
        const int cur = k & 1;
        if (k < 15) {
            const int nxt = cur ^ 1;
            #pragma unroll
            for (int j = 0; j < 16; ++j) {
                const int ei2 = irl(e2idx[j & 3], 4 * (k + 1) + (j >> 2));
                glb_f* g = (glb_f*)(entity_emb + (size_t)ei2 * DIM + lane);
                lds_f* l = (lds_f*)&stage[wave][nxt][j][0];
                __builtin_amdgcn_global_load_lds(g, l, 4, 0, 0);
            }
        }
        __builtin_amdgcn_sched_barrier(0);
        if (k < 15) __builtin_amdgcn_s_waitcnt(0x4F70);  // vmcnt(16): chunk k done
        else        __builtin_amdgcn_s_waitcnt(0x0F70);  // vmcnt(0): last chunk done
        __builtin_amdgcn_sched_barrier(0);

        float acc = 0.f;
        #pragma unroll
        for (int j = 0; j < 16; ++j) {
            const int src = 4 * k + (j >> 2);
            acc += frl(a1[j & 3], src) * stage[wave][cur][j][lane];
        }
        agg0 += frl(attn0, k) * v1a[k];
        xbuf[wave][1 + k][lane] = v1a[k] + acc * (1.0f / KNBR);
    }
    xbuf[wave][0][lane] = ev0 + agg0 * (1.0f / KNBR);
    __syncthreads();

    // Layer-0 matmul: h[r][e] = relu( sum_d x[r][d] * W0[e][d] + b0[e] ), 17 rows
    float h[17];
    {
        #pragma unroll
        for (int r = 0; r < 17; ++r) h[r] = bias0;
        const float4* wrow = (const float4*)(W0 + lane * DIM);
        #pragma unroll
        for (int q = 0; q < 16; ++q) {
            float4 w = wrow[q];   // L1-resident
            #pragma unroll
            for (int r = 0; r < 17; ++r) {
                float4 xv = ((const float4*)xbuf[wave][r])[q];  // broadcast read
                h[r] += xv.x * w.x + xv.y * w.y + xv.z * w.z + xv.w * w.w;
            }
        }
        #pragma unroll
        for (int r = 0; r < 17; ++r) h[r] = fmaxf(h[r], 0.f);
    }

    // Layer-1: agg over h1 with the SAME attn0, then tanh((h0+agg) @ W1^T + b1)
    float aggL = 0.f;
    #pragma unroll
    for (int k = 0; k < KNBR; ++k)
        aggL += frl(attn0, k) * h[1 + k];              // imm-lane readlane
    const float xL = h[0] + aggL * (1.0f / KNBR);
    __syncthreads();
    xbuf[wave][0][lane] = xL;
    __syncthreads();

    float acc1 = b1[lane];
    {
        const float4* wrow = (const float4*)(W1 + lane * DIM);
        const float4* xb   = (const float4*)xbuf[wave][0];
        #pragma unroll
        for (int q = 0; q < 16; ++q) {
            float4 w  = wrow[q];
            float4 xv = xb[q];
            acc1 += xv.x * w.x + xv.y * w.y + xv.z * w.z + xv.w * w.w;
        }
    }
    const float item = tanhf(acc1);

    // score = sigmoid( sum_d ue[d] * item[d] )
    float p = ue * item;
    #pragma unroll
    for (int m = 1; m < 64; m <<= 1) p += __shfl_xor(p, m);
    if (lane == 0) out[b] = 1.0f / (1.0f + __expf(-p));
}

extern "C" void kernel_launch(void* const* d_in, const int* in_sizes, int n_in,
                              void* d_out, int out_size, void* d_ws, size_t ws_size,
                              hipStream_t stream) {
    const int*   u_ids        = (const int*)  d_in[0];
    const int*   i_ids        = (const int*)  d_in[1];
    const int*   adj_entity   = (const int*)  d_in[2];
    const int*   adj_relation = (const int*)  d_in[3];
    const float* user_emb     = (const float*)d_in[4];
    const float* entity_emb   = (const float*)d_in[5];
    const float* relation_emb = (const float*)d_in[6];
    const float* W0           = (const float*)d_in[7];
    const float* b0           = (const float*)d_in[8];
    const float* W1           = (const float*)d_in[9];
    const float* b1           = (const float*)d_in[10];
    float* out = (float*)d_out;

    const int B = in_sizes[0];
    const int grid = (B + WPB - 1) / WPB;
    hipLaunchKernelGGL(kgnnls_kernel, dim3(grid), dim3(64 * WPB), 0, stream,
        u_ids, i_ids, adj_entity, adj_relation, user_emb, entity_emb,
        relation_emb, W0, b0, W1, b1, out, B);
}